// Round 1
// baseline (508.113 us; speedup 1.0000x reference)
//
#include <hip/hip_runtime.h>

// Grouped GRU, G=8 groups, H=I=64. One workgroup per (b,g) chain; 256 threads.
// Thread (j = tid>>2, p = tid&3): owns hidden row j, k-quarter p.
// Weights (6 row-slices of 16 floats) in registers; x_t and h broadcast via LDS.
// DPP quad reduction -> gates computed redundantly on all 4 p-lanes -> 1 barrier/step.
// x streamed via 8-step chunked register prefetch (load ph0, ds_write ph7, dbuf).

#define TPB 256

__device__ __forceinline__ float fast_rcp(float v) { return __builtin_amdgcn_rcpf(v); }
__device__ __forceinline__ float sigm(float v)     { return fast_rcp(1.f + __expf(-v)); }
__device__ __forceinline__ float tanh_f(float v)   { return 1.f - 2.f * fast_rcp(1.f + __expf(2.f * v)); }

__device__ __forceinline__ float4 fma4(float4 a, float4 b, float4 c) {
    c.x = __builtin_fmaf(a.x, b.x, c.x);
    c.y = __builtin_fmaf(a.y, b.y, c.y);
    c.z = __builtin_fmaf(a.z, b.z, c.z);
    c.w = __builtin_fmaf(a.w, b.w, c.w);
    return c;
}

// sum across lane quads {4k..4k+3} via DPP (quad_perm swaps): pure VALU, no LDS pipe.
__device__ __forceinline__ float qsum4(float v) {
    int a = __builtin_amdgcn_mov_dpp(__float_as_int(v), 0xB1, 0xF, 0xF, true); // [1,0,3,2]
    v += __int_as_float(a);
    int b = __builtin_amdgcn_mov_dpp(__float_as_int(v), 0x4E, 0xF, 0xF, true); // [2,3,0,1]
    v += __int_as_float(b);
    return v;
}

__global__ __launch_bounds__(TPB, 1)
void gru_fused(const float* __restrict__ x, const float* __restrict__ h0,
               const float* __restrict__ Wih, const float* __restrict__ Whh,
               const float* __restrict__ bih, const float* __restrict__ bhh,
               float* __restrict__ out, float* __restrict__ hout,
               int B, int T)
{
    const int bid = blockIdx.x;
    const int g   = bid & 7;
    const int b   = bid >> 3;
    const int tid = threadIdx.x;
    const int j   = tid >> 2;    // hidden row 0..63
    const int p   = tid & 3;     // k-quarter 0..3

    // x chunk staging: 8 timesteps * 64 feats = 512 floats; 2 floats/thread
    const int e0  = tid * 2;
    const int phx = e0 >> 6;     // which timestep-within-chunk this thread stages
    const int ix  = e0 & 63;     // feature index

    __shared__ float xsc[2][512];
    __shared__ float hs[2][64];

    const size_t gw = (size_t)g * 192 * 64;
    const float* WhG = Whh + gw;
    const float* WiG = Wih + gw;
    float4 whr[4], whz[4], whn[4], wxr[4], wxz[4], wxn[4];
#pragma unroll
    for (int i = 0; i < 4; ++i) {
        const int col = p * 16 + i * 4;
        whr[i] = *(const float4*)(WhG + (j      ) * 64 + col);
        whz[i] = *(const float4*)(WhG + (j +  64) * 64 + col);
        whn[i] = *(const float4*)(WhG + (j + 128) * 64 + col);
        wxr[i] = *(const float4*)(WiG + (j      ) * 64 + col);
        wxz[i] = *(const float4*)(WiG + (j +  64) * 64 + col);
        wxn[i] = *(const float4*)(WiG + (j + 128) * 64 + col);
    }
    const float* bihG = bih + g * 192;
    const float* bhhG = bhh + g * 192;
    const float b_r  = bihG[j]      + bhhG[j];
    const float b_z  = bihG[64 + j] + bhhG[64 + j];
    const float bi_n = bihG[128 + j];
    const float bh_n = bhhG[128 + j];   // r multiplies (gh_n + bhh_n) only

    float h_reg = h0[((size_t)g * B + b) * 64 + j];
    if (p == 0) hs[0][j] = h_reg;

    const float* xb = x + (size_t)b * T * 512 + (size_t)g * 64;

    // stage chunk 0 (timesteps 0..7)
    float2 cnext = make_float2(0.f, 0.f);
    {
        float2 c0 = make_float2(0.f, 0.f);
        if (phx < T) c0 = *(const float2*)(xb + (size_t)phx * 512 + ix);
        *(float2*)&xsc[0][e0] = c0;
    }
    asm volatile("s_waitcnt lgkmcnt(0)" ::: "memory");
    __builtin_amdgcn_s_barrier();
    asm volatile("" ::: "memory");

    float* outp = out + (size_t)b * T * 512 + (size_t)g * 64 + j;

    for (int t8 = 0; t8 < T; t8 += 8) {
        const int bufi = (t8 >> 3) & 1;
        const float* xcb = &xsc[bufi][0];
#pragma unroll
        for (int ph = 0; ph < 8; ++ph) {
            const int t = t8 + ph;
            if (t >= T) break;   // uniform

            // issue next-chunk global loads at phase 0 (in flight ~7 steps)
            if (ph == 0 && t8 + 8 < T)
                cnext = *(const float2*)(xb + (size_t)(t8 + 8 + phx) * 512 + ix);

            const float* hp = &hs[ph & 1][p * 16];
            const float* xp = xcb + ph * 64 + p * 16;

            float4 ar  = make_float4(0.f, 0.f, 0.f, 0.f);
            float4 az  = make_float4(0.f, 0.f, 0.f, 0.f);
            float4 axn = make_float4(0.f, 0.f, 0.f, 0.f);
            float4 ahn = make_float4(0.f, 0.f, 0.f, 0.f);
#pragma unroll
            for (int i = 0; i < 4; ++i) {
                const float4 hv = *(const float4*)(hp + i * 4);
                const float4 xv = *(const float4*)(xp + i * 4);
                ar  = fma4(whr[i], hv, ar);
                az  = fma4(whz[i], hv, az);
                ahn = fma4(whn[i], hv, ahn);
                ar  = fma4(wxr[i], xv, ar);
                az  = fma4(wxz[i], xv, az);
                axn = fma4(wxn[i], xv, axn);
            }
            float sr  = (ar.x  + ar.y ) + (ar.z  + ar.w );
            float sz  = (az.x  + az.y ) + (az.z  + az.w );
            float sxn = (axn.x + axn.y) + (axn.z + axn.w);
            float shn = (ahn.x + ahn.y) + (ahn.z + ahn.w);
            sr = qsum4(sr); sz = qsum4(sz); sxn = qsum4(sxn); shn = qsum4(shn);

            const float r  = sigm(sr + b_r);
            const float zg = sigm(sz + b_z);
            const float nv = tanh_f(sxn + bi_n + r * (shn + bh_n));
            h_reg = nv + zg * (h_reg - nv);   // (1-z)*n + z*h

            if (p == 0) hs[(ph & 1) ^ 1][j] = h_reg;       // next-step h (double-buffered)
            if (p == 1) outp[(size_t)t * 512] = h_reg;     // output row t

            // ds_write next-chunk x at phase 7 (compiler inserts the vmcnt wait on cnext)
            if (ph == 7 && t8 + 8 < T)
                *(float2*)&xsc[bufi ^ 1][e0] = cnext;

            asm volatile("s_waitcnt lgkmcnt(0)" ::: "memory");
            __builtin_amdgcn_s_barrier();
            asm volatile("" ::: "memory");
        }
    }

    if (p == 0) hout[((size_t)g * B + b) * 64 + j] = h_reg;   // h_final [G,B,H]
}

extern "C" void kernel_launch(void* const* d_in, const int* in_sizes, int n_in,
                              void* d_out, int out_size, void* d_ws, size_t ws_size,
                              hipStream_t stream) {
    (void)n_in; (void)d_ws; (void)ws_size; (void)out_size;
    const float* x   = (const float*)d_in[0];
    const float* h0  = (const float*)d_in[1];
    const float* Wih = (const float*)d_in[2];
    const float* Whh = (const float*)d_in[3];
    const float* bih = (const float*)d_in[4];
    const float* bhh = (const float*)d_in[5];

    const int B = in_sizes[1] / 512;                 // h0 = G*B*H = 8*B*64
    const int T = (int)((long long)in_sizes[0] / ((long long)B * 512)); // x = B*T*512

    float* out  = (float*)d_out;
    float* hout = out + (size_t)B * T * 512;

    dim3 grid(B * 8), block(TPB);
    hipLaunchKernelGGL(gru_fused, grid, block, 0, stream,
                       x, h0, Wih, Whh, bih, bhh, out, hout, B, T);
}